// Round 2
// baseline (1275.008 us; speedup 1.0000x reference)
//
#include <hip/hip_runtime.h>
#include <stdint.h>

#define BB 2
#define SS 2048
#define EE 256
#define HH 8
#define DDh 32

// ---------- block reductions (256 threads = 4 waves of 64) ----------
__device__ __forceinline__ float blockSum(float v, float* red){
  #pragma unroll
  for (int off = 32; off > 0; off >>= 1) v += __shfl_xor(v, off, 64);
  int w = threadIdx.x >> 6;
  if ((threadIdx.x & 63) == 0) red[w] = v;
  __syncthreads();
  float r = (red[0] + red[1]) + (red[2] + red[3]);
  __syncthreads();
  return r;
}
__device__ __forceinline__ float blockMax(float v, float* red){
  #pragma unroll
  for (int off = 32; off > 0; off >>= 1) v = fmaxf(v, __shfl_xor(v, off, 64));
  int w = threadIdx.x >> 6;
  if ((threadIdx.x & 63) == 0) red[w] = v;
  __syncthreads();
  float r = fmaxf(fmaxf(red[0], red[1]), fmaxf(red[2], red[3]));
  __syncthreads();
  return r;
}

// ---------- K0: LayerNorm (no affine), one block per (b,s) row ----------
__global__ __launch_bounds__(256) void k_ln(const float* __restrict__ x,
                                            float* __restrict__ xn){
  __shared__ float red[4];
  int row = blockIdx.x, t = threadIdx.x;
  float xv = x[(size_t)row * EE + t];
  float s  = blockSum(xv, red);
  float ss = blockSum(xv * xv, red);
  float mean = s * (1.0f / EE);
  float var  = ss * (1.0f / EE) - mean * mean;
  float rstd = rsqrtf(var + 1e-5f);
  xn[(size_t)row * EE + t] = (xv - mean) * rstd;
}

// ---------- K1: fused q/k/v/gate projection. 8 rows per block; thread t
// owns output column t of all 4 weight matrices. x values are wave-uniform
// global loads (compiler scalarizes) -> no LDS broadcast cost.
__global__ __launch_bounds__(256) void k_proj(const float* __restrict__ xn,
    const float* __restrict__ Wq, const float* __restrict__ Wk,
    const float* __restrict__ Wv, const float* __restrict__ Wg,
    const float* __restrict__ bg,
    float* __restrict__ qws, float* __restrict__ kws,
    float* __restrict__ vws, float* __restrict__ gws){
  int t  = threadIdx.x;
  int r0 = blockIdx.x * 8;
  const float* xr = xn + (size_t)r0 * EE;
  const float4* wq4 = (const float4*)(Wq + (size_t)t * EE);
  const float4* wk4 = (const float4*)(Wk + (size_t)t * EE);
  const float4* wv4 = (const float4*)(Wv + (size_t)t * EE);
  const float4* wg4 = (const float4*)(Wg + (size_t)t * EE);
  float aq[8] = {0,0,0,0,0,0,0,0}, ak[8] = {0,0,0,0,0,0,0,0};
  float av[8] = {0,0,0,0,0,0,0,0}, ag[8] = {0,0,0,0,0,0,0,0};
  for (int c = 0; c < 64; ++c){
    float4 q4 = wq4[c], k4 = wk4[c], v4 = wv4[c], g4 = wg4[c];
    float fq[4] = {q4.x,q4.y,q4.z,q4.w};
    float fk[4] = {k4.x,k4.y,k4.z,k4.w};
    float fv[4] = {v4.x,v4.y,v4.z,v4.w};
    float fg[4] = {g4.x,g4.y,g4.z,g4.w};
    #pragma unroll
    for (int p = 0; p < 4; ++p){
      int e = c * 4 + p;
      #pragma unroll
      for (int rr = 0; rr < 8; ++rr){
        float xv = xr[rr * EE + e];
        aq[rr] = fmaf(xv, fq[p], aq[rr]);
        ak[rr] = fmaf(xv, fk[p], ak[rr]);
        av[rr] = fmaf(xv, fv[p], av[rr]);
        ag[rr] = fmaf(xv, fg[p], ag[rr]);
      }
    }
  }
  float bgv = bg[t];
  int h = t >> 5, d = t & 31;
  #pragma unroll
  for (int rr = 0; rr < 8; ++rr){
    int row = r0 + rr;
    int b = row >> 11, s2 = row & (SS - 1);
    size_t o = (((size_t)b * HH + h) * SS + s2) * DDh + d;
    qws[o] = aq[rr] * 0.17677669529663687f;   // 1/sqrt(D)
    kws[o] = ak[rr];
    vws[o] = av[rr];
    gws[o] = 1.0f / (1.0f + __expf(-(ag[rr] + bgv)));
  }
}

// ---------- K2: attention, two-pass softmax, 2 query rows per block.
// Q in registers (64 f32); logits in registers through max/exp/sum;
// P staged once through LDS (bank-staggered) for the PV phase.
__global__ __launch_bounds__(256) void k_attn(const float* __restrict__ qws,
    const float* __restrict__ kws, const float* __restrict__ vws,
    const float* __restrict__ gws, const float* __restrict__ bias,
    const float* __restrict__ mask, float* __restrict__ gout){
  __shared__ float plg[2 * SS];   // 16 KB: p values, then reused for partials
  __shared__ float red[4];
  int t  = threadIdx.x;
  int bh = blockIdx.x >> 10;            // 1024 blocks per (b,h)
  int i0 = (blockIdx.x & 1023) << 1;    // 2 query rows
  int b = bh >> 3, h = bh & 7;

  // Q rows in registers: 2 x 32 f32
  float qf[2][DDh];
  const float4* qp4 = (const float4*)(qws + ((size_t)bh * SS + i0) * DDh);
  #pragma unroll
  for (int r = 0; r < 2; ++r)
    #pragma unroll
    for (int p = 0; p < 8; ++p){
      float4 qv = qp4[r * 8 + p];
      qf[r][p*4] = qv.x; qf[r][p*4+1] = qv.y; qf[r][p*4+2] = qv.z; qf[r][p*4+3] = qv.w;
    }

  const float* kb   = kws  + (size_t)bh * SS * DDh;
  const float* br   = bias + ((size_t)bh * SS + i0) * SS;
  const float* mrow = mask + (size_t)b * SS;

  float lg[2][8];
  for (int jc = 0; jc < 8; ++jc){
    int j = jc * 256 + t;
    const float4* kr = (const float4*)(kb + (size_t)j * DDh);
    float kf[DDh];
    #pragma unroll
    for (int q4 = 0; q4 < 8; ++q4){
      float4 kv = kr[q4];
      kf[q4*4] = kv.x; kf[q4*4+1] = kv.y; kf[q4*4+2] = kv.z; kf[q4*4+3] = kv.w;
    }
    float mv  = mrow[j];
    bool keep = (mv >= 0.5f);
    #pragma unroll
    for (int r = 0; r < 2; ++r){
      float acc = 0.0f;
      #pragma unroll
      for (int d = 0; d < DDh; ++d)
        acc = fmaf(qf[r][d], kf[d], acc);
      float bv = br[(size_t)r * SS + j];
      lg[r][jc] = keep ? (acc + bv) : -32768.0f;   // -INF = -2^15 exactly
    }
  }

  float mm[2], inv[2];
  #pragma unroll
  for (int r = 0; r < 2; ++r){
    float lm = -3.4e38f;
    #pragma unroll
    for (int jc = 0; jc < 8; ++jc) lm = fmaxf(lm, lg[r][jc]);
    mm[r] = blockMax(lm, red);
  }
  #pragma unroll
  for (int r = 0; r < 2; ++r){
    float s = 0.0f;
    #pragma unroll
    for (int jc = 0; jc < 8; ++jc){
      float p = __expf(lg[r][jc] - mm[r]);
      lg[r][jc] = p; s += p;
    }
    float l = blockSum(s, red);
    inv[r] = 1.0f / l;
  }
  #pragma unroll
  for (int r = 0; r < 2; ++r)
    #pragma unroll
    for (int jc = 0; jc < 8; ++jc)
      plg[r * SS + jc * 256 + t] = lg[r][jc];
  __syncthreads();

  // PV: thread = (dg in 0..3 -> 8 d's, c5 in 0..63 -> 32 j's).
  // j staggered by c5 so the stride-32-float p reads spread across banks.
  int dg = t & 3, c5 = t >> 2;
  const float* vb = vws + (size_t)bh * SS * DDh;
  float acc[2][8];
  #pragma unroll
  for (int r = 0; r < 2; ++r)
    #pragma unroll
    for (int kq = 0; kq < 8; ++kq) acc[r][kq] = 0.0f;
  for (int jj = 0; jj < 32; ++jj){
    int j = c5 * 32 + ((jj + c5) & 31);
    const float4* vr = (const float4*)(vb + (size_t)j * DDh);
    float4 va = vr[dg * 2], vbv = vr[dg * 2 + 1];
    float vf[8] = {va.x, va.y, va.z, va.w, vbv.x, vbv.y, vbv.z, vbv.w};
    #pragma unroll
    for (int r = 0; r < 2; ++r){
      float p = plg[r * SS + j];
      #pragma unroll
      for (int kq = 0; kq < 8; ++kq)
        acc[r][kq] = fmaf(p, vf[kq], acc[r][kq]);
    }
  }
  __syncthreads();   // everyone done reading p; reuse plg for partials
  #pragma unroll
  for (int r = 0; r < 2; ++r){
    float4 lo = make_float4(acc[r][0], acc[r][1], acc[r][2], acc[r][3]);
    float4 hi = make_float4(acc[r][4], acc[r][5], acc[r][6], acc[r][7]);
    *(float4*)&plg[r * SS + c5 * 32 + dg * 8]     = lo;
    *(float4*)&plg[r * SS + c5 * 32 + dg * 8 + 4] = hi;
  }
  __syncthreads();
  if (t < 64){
    int r = t >> 5, d = t & 31;
    float s = 0.0f;
    #pragma unroll
    for (int c = 0; c < 64; ++c) s += plg[r * SS + c * 32 + d];
    s *= inv[r];
    float gv = gws[((size_t)bh * SS + i0 + r) * DDh + d];
    s *= gv;
    gout[((size_t)b * SS + (i0 + r)) * EE + h * DDh + d] = s;
  }
}

// ---------- K3: output projection. 8 rows/block; thread t owns output e=t.
// gout values are wave-uniform loads (scalarized) -> no LDS.
__global__ __launch_bounds__(256) void k_out(const float* __restrict__ gout,
    const float* __restrict__ Wo, const float* __restrict__ bo,
    float* __restrict__ out){
  int t  = threadIdx.x;
  int r0 = blockIdx.x * 8;
  const float*  gr  = gout + (size_t)r0 * EE;
  const float4* wo4 = (const float4*)(Wo + (size_t)t * EE);
  float acc[8] = {0,0,0,0,0,0,0,0};
  for (int c = 0; c < 64; ++c){
    float4 w4 = wo4[c];
    float fw[4] = {w4.x, w4.y, w4.z, w4.w};
    #pragma unroll
    for (int p = 0; p < 4; ++p){
      int e = c * 4 + p;
      #pragma unroll
      for (int rr = 0; rr < 8; ++rr)
        acc[rr] = fmaf(gr[rr * EE + e], fw[p], acc[rr]);
    }
  }
  float bov = bo[t];
  #pragma unroll
  for (int rr = 0; rr < 8; ++rr)
    out[(size_t)(r0 + rr) * EE + t] = acc[rr] + bov;
}

extern "C" void kernel_launch(void* const* d_in, const int* in_sizes, int n_in,
                              void* d_out, int out_size, void* d_ws, size_t ws_size,
                              hipStream_t stream){
  const float* x    = (const float*)d_in[0];
  const float* mask = (const float*)d_in[1];
  const float* bias = (const float*)d_in[2];
  const float* Wq   = (const float*)d_in[3];
  const float* Wk   = (const float*)d_in[4];
  const float* Wv   = (const float*)d_in[5];
  const float* Wg   = (const float*)d_in[6];
  const float* bg   = (const float*)d_in[7];
  const float* Wo   = (const float*)d_in[8];
  const float* bo   = (const float*)d_in[9];
  float* out = (float*)d_out;

  char* ws = (char*)d_ws;
  float* xn  = (float*)ws;                    // 4 MB  [B*S, E]
  float* qws = (float*)(ws + (4  << 20));     // 4 MB  [B,H,S,D] (pre-scaled)
  float* kws = (float*)(ws + (8  << 20));     // 4 MB
  float* vws = (float*)(ws + (12 << 20));     // 4 MB
  float* gws = (float*)(ws + (16 << 20));     // 4 MB  sigmoid gate
  float* gout= (float*)(ws + (20 << 20));     // 4 MB  [B,S,H*D] gated attn out

  hipLaunchKernelGGL(k_ln,   dim3(BB * SS),            dim3(256), 0, stream, x, xn);
  hipLaunchKernelGGL(k_proj, dim3(BB * SS / 8),        dim3(256), 0, stream,
                     xn, Wq, Wk, Wv, Wg, bg, qws, kws, vws, gws);
  hipLaunchKernelGGL(k_attn, dim3(BB * HH * (SS / 2)), dim3(256), 0, stream,
                     qws, kws, vws, gws, bias, mask, gout);
  hipLaunchKernelGGL(k_out,  dim3(BB * SS / 8),        dim3(256), 0, stream,
                     gout, Wo, bo, out);
}

// Round 3
// 558.539 us; speedup vs baseline: 2.2828x; 2.2828x over previous
//
#include <hip/hip_runtime.h>
#include <stdint.h>

typedef unsigned short u16;
typedef unsigned int   u32;
typedef __attribute__((ext_vector_type(8))) short short8;   // 8 bf16 = 4 VGPRs
typedef __attribute__((ext_vector_type(4))) float f32x4;

#define BB 2
#define SS 2048
#define EE 256
#define HH 8
#define DDh 32

// ---------- bf16 helpers ----------
__device__ __forceinline__ u16 f2b(float f){   // round-to-nearest-even
  union{u32 u; float f;} c; c.f = f;
  u32 r = c.u + 0x7fffu + ((c.u >> 16) & 1u);
  return (u16)(r >> 16);
}
__device__ __forceinline__ u32 pack2(float lo, float hi){
  return (u32)f2b(lo) | ((u32)f2b(hi) << 16);
}

// ---------- block reductions (256 threads = 4 waves of 64) ----------
__device__ __forceinline__ float blockSum(float v, float* red){
  #pragma unroll
  for (int off = 32; off > 0; off >>= 1) v += __shfl_xor(v, off, 64);
  int w = threadIdx.x >> 6;
  if ((threadIdx.x & 63) == 0) red[w] = v;
  __syncthreads();
  float r = (red[0] + red[1]) + (red[2] + red[3]);
  __syncthreads();
  return r;
}

// ---------- K0: LayerNorm (no affine), one block per (b,s) row ----------
__global__ __launch_bounds__(256) void k_ln(const float* __restrict__ x,
                                            float* __restrict__ xn){
  __shared__ float red[4];
  int row = blockIdx.x, t = threadIdx.x;
  float xv = x[(size_t)row * EE + t];
  float s  = blockSum(xv, red);
  float ss = blockSum(xv * xv, red);
  float mean = s * (1.0f / EE);
  float var  = ss * (1.0f / EE) - mean * mean;
  float rstd = rsqrtf(var + 1e-5f);
  xn[(size_t)row * EE + t] = (xv - mean) * rstd;
}

// ---------- K1: fused q/k/v/gate projection. 8 rows per block; thread t
// owns output column t. Emits bf16 Q (pre-scaled) / K row-major [bh][S][32],
// bf16 V TRANSPOSED [bh][32][S], f32 gate [bh][S][32].
__global__ __launch_bounds__(256) void k_proj(const float* __restrict__ xn,
    const float* __restrict__ Wq, const float* __restrict__ Wk,
    const float* __restrict__ Wv, const float* __restrict__ Wg,
    const float* __restrict__ bg,
    u16* __restrict__ qws, u16* __restrict__ kws,
    u16* __restrict__ vtws, float* __restrict__ gws){
  int t  = threadIdx.x;
  int r0 = blockIdx.x * 8;
  const float* xr = xn + (size_t)r0 * EE;
  const float4* wq4 = (const float4*)(Wq + (size_t)t * EE);
  const float4* wk4 = (const float4*)(Wk + (size_t)t * EE);
  const float4* wv4 = (const float4*)(Wv + (size_t)t * EE);
  const float4* wg4 = (const float4*)(Wg + (size_t)t * EE);
  float aq[8] = {0,0,0,0,0,0,0,0}, ak[8] = {0,0,0,0,0,0,0,0};
  float av[8] = {0,0,0,0,0,0,0,0}, ag[8] = {0,0,0,0,0,0,0,0};
  for (int c = 0; c < 64; ++c){
    float4 q4 = wq4[c], k4 = wk4[c], v4 = wv4[c], g4 = wg4[c];
    float fq[4] = {q4.x,q4.y,q4.z,q4.w};
    float fk[4] = {k4.x,k4.y,k4.z,k4.w};
    float fv[4] = {v4.x,v4.y,v4.z,v4.w};
    float fg[4] = {g4.x,g4.y,g4.z,g4.w};
    #pragma unroll
    for (int p = 0; p < 4; ++p){
      int e = c * 4 + p;
      #pragma unroll
      for (int rr = 0; rr < 8; ++rr){
        float xv = xr[rr * EE + e];
        aq[rr] = fmaf(xv, fq[p], aq[rr]);
        ak[rr] = fmaf(xv, fk[p], ak[rr]);
        av[rr] = fmaf(xv, fv[p], av[rr]);
        ag[rr] = fmaf(xv, fg[p], ag[rr]);
      }
    }
  }
  float bgv = bg[t];
  int h = t >> 5, d = t & 31;
  int b = r0 >> 11, s0 = r0 & (SS - 1);      // all 8 rows share b
  u16 vtmp[8];
  #pragma unroll
  for (int rr = 0; rr < 8; ++rr){
    size_t o = (((size_t)b * HH + h) * SS + (s0 + rr)) * DDh + d;
    qws[o] = f2b(aq[rr] * 0.17677669529663687f);   // 1/sqrt(D)
    kws[o] = f2b(ak[rr]);
    gws[o] = 1.0f / (1.0f + __expf(-(ag[rr] + bgv)));
    vtmp[rr] = f2b(av[rr]);
  }
  // V^T: row (h,d), 8 consecutive s -> one 16B store
  *(uint4*)(vtws + (((size_t)b * HH + h) * DDh + d) * SS + s0) = *(uint4*)vtmp;
}

// ---------- K2: flash attention on MFMA. One wave = 16 query rows.
// S^T = K·Q^T so query index lives in lane&15 -> softmax reductions are
// 2 shfl_xor; P^T enters the PV MFMA (O^T = V^T·P^T) after a quad shuffle.
// Zero LDS, zero barriers.
__global__ __launch_bounds__(256) void k_attn(const u16* __restrict__ qws,
    const u16* __restrict__ kws, const u16* __restrict__ vtws,
    const float* __restrict__ gws, const float* __restrict__ bias,
    const float* __restrict__ mask, float* __restrict__ gout){
  int t = threadIdx.x;
  int wave = t >> 6, lane = t & 63;
  int q4 = lane >> 4, ln = lane & 15;     // quad, lane-in-16
  int bh = blockIdx.x >> 5;               // 32 blocks per (b,h)
  int i0 = (blockIdx.x & 31) * 64 + wave * 16;
  int b = bh >> 3, h = bh & 7;

  // B-frag of Q^T: n=ln -> query i0+ln, k=q4*8+e -> d
  short8 qf = *(const short8*)(qws + (((size_t)bh * SS + i0 + ln) * DDh) + q4 * 8);

  const u16*  kb   = kws  + (size_t)bh * SS * DDh;
  const u16*  vt   = vtws + (size_t)bh * DDh * SS;
  const float* br  = bias + ((size_t)bh * SS + i0) * SS;
  const float* mrow= mask + (size_t)b * SS;

  f32x4 O0 = {0.f,0.f,0.f,0.f}, O1 = {0.f,0.f,0.f,0.f};
  float m_run = -INFINITY, l_run = 0.0f;
  const f32x4 zero = {0.f,0.f,0.f,0.f};

  for (int j0 = 0; j0 < SS; j0 += 32){
    // ---- loads for this tile (all independent of softmax state) ----
    short8 ka0 = *(const short8*)(kb + (size_t)(j0 + ln)      * DDh + q4 * 8);
    short8 ka1 = *(const short8*)(kb + (size_t)(j0 + 16 + ln) * DDh + q4 * 8);
    short8 va0 = *(const short8*)(vt + (size_t)ln        * SS + j0 + q4 * 8);
    short8 va1 = *(const short8*)(vt + (size_t)(16 + ln) * SS + j0 + q4 * 8);
    float4 bv0 = *(const float4*)(br + (size_t)ln * SS + j0 + q4 * 4);
    float4 bv1 = *(const float4*)(br + (size_t)ln * SS + j0 + 16 + q4 * 4);
    float4 mv0 = *(const float4*)(mrow + j0 + q4 * 4);
    float4 mv1 = *(const float4*)(mrow + j0 + 16 + q4 * 4);

    // ---- scores: S^T rows j (quad*4+reg), cols i (ln) ----
    f32x4 s0 = __builtin_amdgcn_mfma_f32_16x16x32_bf16(ka0, qf, zero, 0, 0, 0);
    f32x4 s1 = __builtin_amdgcn_mfma_f32_16x16x32_bf16(ka1, qf, zero, 0, 0, 0);

    float lgv[8];
    lgv[0] = (mv0.x >= 0.5f) ? s0[0] + bv0.x : -32768.0f;
    lgv[1] = (mv0.y >= 0.5f) ? s0[1] + bv0.y : -32768.0f;
    lgv[2] = (mv0.z >= 0.5f) ? s0[2] + bv0.z : -32768.0f;
    lgv[3] = (mv0.w >= 0.5f) ? s0[3] + bv0.w : -32768.0f;
    lgv[4] = (mv1.x >= 0.5f) ? s1[0] + bv1.x : -32768.0f;
    lgv[5] = (mv1.y >= 0.5f) ? s1[1] + bv1.y : -32768.0f;
    lgv[6] = (mv1.z >= 0.5f) ? s1[2] + bv1.z : -32768.0f;
    lgv[7] = (mv1.w >= 0.5f) ? s1[3] + bv1.w : -32768.0f;

    // ---- online softmax (per query i = ln; broadcast across quads) ----
    float mt = lgv[0];
    #pragma unroll
    for (int r = 1; r < 8; ++r) mt = fmaxf(mt, lgv[r]);
    mt = fmaxf(mt, __shfl_xor(mt, 16, 64));
    mt = fmaxf(mt, __shfl_xor(mt, 32, 64));
    float m_new = fmaxf(m_run, mt);
    float alpha = __expf(m_run - m_new);
    float p[8], ts = 0.0f;
    #pragma unroll
    for (int r = 0; r < 8; ++r){ p[r] = __expf(lgv[r] - m_new); ts += p[r]; }
    ts += __shfl_xor(ts, 16, 64);
    ts += __shfl_xor(ts, 32, 64);
    l_run = l_run * alpha + ts;
    m_run = m_new;
    #pragma unroll
    for (int e = 0; e < 4; ++e){ O0[e] *= alpha; O1[e] *= alpha; }

    // ---- P^T C-layout -> B-operand layout (quad shuffle) ----
    u32 P0 = pack2(p[0], p[1]), P1 = pack2(p[2], p[3]);
    u32 P2 = pack2(p[4], p[5]), P3 = pack2(p[6], p[7]);
    int sl  = (q4 & 1) * 32 + ln;   // source lane for j = 8q..8q+3
    int sl2 = sl + 16;              // source lane for j = 8q+4..8q+7
    u32 x0 = __shfl((int)P0, sl,  64), x1 = __shfl((int)P1, sl,  64);
    u32 x2 = __shfl((int)P2, sl,  64), x3 = __shfl((int)P3, sl,  64);
    u32 y0 = __shfl((int)P0, sl2, 64), y1 = __shfl((int)P1, sl2, 64);
    u32 y2 = __shfl((int)P2, sl2, 64), y3 = __shfl((int)P3, sl2, 64);
    bool lo = (q4 < 2);
    u32 bb[4];
    bb[0] = lo ? x0 : x2;  bb[1] = lo ? x1 : x3;
    bb[2] = lo ? y0 : y2;  bb[3] = lo ? y1 : y3;
    short8 pf = *(short8*)bb;

    // ---- O^T += V^T · P^T ----
    O0 = __builtin_amdgcn_mfma_f32_16x16x32_bf16(va0, pf, O0, 0, 0, 0);
    O1 = __builtin_amdgcn_mfma_f32_16x16x32_bf16(va1, pf, O1, 0, 0, 0);
  }

  // ---- epilogue: O^T rows d = q4*4+reg (+16 for O1), col i = ln ----
  float inv = 1.0f / l_run;
  const float* gr = gws + ((size_t)bh * SS + i0 + ln) * DDh;
  float4 g0 = *(const float4*)(gr + q4 * 4);
  float4 g1 = *(const float4*)(gr + 16 + q4 * 4);
  float* orow = gout + ((size_t)b * SS + (i0 + ln)) * EE + h * DDh;
  float4 w0, w1;
  w0.x = O0[0] * inv * g0.x;  w0.y = O0[1] * inv * g0.y;
  w0.z = O0[2] * inv * g0.z;  w0.w = O0[3] * inv * g0.w;
  w1.x = O1[0] * inv * g1.x;  w1.y = O1[1] * inv * g1.y;
  w1.z = O1[2] * inv * g1.z;  w1.w = O1[3] * inv * g1.w;
  *(float4*)(orow + q4 * 4)      = w0;
  *(float4*)(orow + 16 + q4 * 4) = w1;
}

// ---------- K3: output projection. 8 rows/block; thread t owns output e=t.
__global__ __launch_bounds__(256) void k_out(const float* __restrict__ gout,
    const float* __restrict__ Wo, const float* __restrict__ bo,
    float* __restrict__ out){
  int t  = threadIdx.x;
  int r0 = blockIdx.x * 8;
  const float*  gr  = gout + (size_t)r0 * EE;
  const float4* wo4 = (const float4*)(Wo + (size_t)t * EE);
  float acc[8] = {0,0,0,0,0,0,0,0};
  for (int c = 0; c < 64; ++c){
    float4 w4 = wo4[c];
    float fw[4] = {w4.x, w4.y, w4.z, w4.w};
    #pragma unroll
    for (int p = 0; p < 4; ++p){
      int e = c * 4 + p;
      #pragma unroll
      for (int rr = 0; rr < 8; ++rr)
        acc[rr] = fmaf(gr[rr * EE + e], fw[p], acc[rr]);
    }
  }
  float bov = bo[t];
  #pragma unroll
  for (int rr = 0; rr < 8; ++rr)
    out[(size_t)(r0 + rr) * EE + t] = acc[rr] + bov;
}

extern "C" void kernel_launch(void* const* d_in, const int* in_sizes, int n_in,
                              void* d_out, int out_size, void* d_ws, size_t ws_size,
                              hipStream_t stream){
  const float* x    = (const float*)d_in[0];
  const float* mask = (const float*)d_in[1];
  const float* bias = (const float*)d_in[2];
  const float* Wq   = (const float*)d_in[3];
  const float* Wk   = (const float*)d_in[4];
  const float* Wv   = (const float*)d_in[5];
  const float* Wg   = (const float*)d_in[6];
  const float* bg   = (const float*)d_in[7];
  const float* Wo   = (const float*)d_in[8];
  const float* bo   = (const float*)d_in[9];
  float* out = (float*)d_out;

  char* ws = (char*)d_ws;
  float* xn  = (float*)ws;                    // 4 MB  [B*S, E] f32
  u16*  qws  = (u16*) (ws + (4  << 20));      // 2 MB  [bh][S][32] bf16, pre-scaled
  u16*  kws  = (u16*) (ws + (6  << 20));      // 2 MB  [bh][S][32] bf16
  u16*  vtws = (u16*) (ws + (8  << 20));      // 2 MB  [bh][32][S] bf16 (transposed)
  float* gws = (float*)(ws + (10 << 20));     // 4 MB  [bh][S][32] f32 sigmoid gate
  float* gout= (float*)(ws + (14 << 20));     // 4 MB  [b][S][256] f32

  hipLaunchKernelGGL(k_ln,   dim3(BB * SS),             dim3(256), 0, stream, x, xn);
  hipLaunchKernelGGL(k_proj, dim3(BB * SS / 8),         dim3(256), 0, stream,
                     xn, Wq, Wk, Wv, Wg, bg, qws, kws, vtws, gws);
  hipLaunchKernelGGL(k_attn, dim3(BB * HH * (SS / 64)), dim3(256), 0, stream,
                     qws, kws, vtws, gws, bias, mask, gout);
  hipLaunchKernelGGL(k_out,  dim3(BB * SS / 8),         dim3(256), 0, stream,
                     gout, Wo, bo, out);
}

// Round 4
// 443.669 us; speedup vs baseline: 2.8738x; 1.2589x over previous
//
#include <hip/hip_runtime.h>
#include <stdint.h>

typedef unsigned short u16;
typedef unsigned int   u32;
typedef __attribute__((ext_vector_type(8))) short    short8;  // 8 bf16 = 4 VGPRs
typedef __attribute__((ext_vector_type(8))) _Float16 half8;   // 8 fp16 = 4 VGPRs
typedef __attribute__((ext_vector_type(4))) _Float16 half4;
typedef __attribute__((ext_vector_type(4))) float    f32x4;

#define BB 2
#define SS 2048
#define EE 256
#define HH 8
#define DDh 32

// ---------- bf16 helpers ----------
__device__ __forceinline__ u16 f2b(float f){   // round-to-nearest-even
  union{u32 u; float f;} c; c.f = f;
  u32 r = c.u + 0x7fffu + ((c.u >> 16) & 1u);
  return (u16)(r >> 16);
}
__device__ __forceinline__ u32 pack2(float lo, float hi){
  return (u32)f2b(lo) | ((u32)f2b(hi) << 16);
}

// ---------- block reductions (256 threads = 4 waves of 64) ----------
__device__ __forceinline__ float blockSum(float v, float* red){
  #pragma unroll
  for (int off = 32; off > 0; off >>= 1) v += __shfl_xor(v, off, 64);
  int w = threadIdx.x >> 6;
  if ((threadIdx.x & 63) == 0) red[w] = v;
  __syncthreads();
  float r = (red[0] + red[1]) + (red[2] + red[3]);
  __syncthreads();
  return r;
}

// ---------- K-1: weight f32 -> fp16 convert (Wq|Wk|Wv|Wg -> wcat, Wo -> woh)
__global__ __launch_bounds__(256) void k_cvt(const float* __restrict__ Wq,
    const float* __restrict__ Wk, const float* __restrict__ Wv,
    const float* __restrict__ Wg, const float* __restrict__ Wo,
    _Float16* __restrict__ wcat, _Float16* __restrict__ woh){
  int id = blockIdx.x * 256 + threadIdx.x;       // 81920 = 5 * 16384
  int g = id >> 14, idx = id & 16383;
  const float* srcs[5] = {Wq, Wk, Wv, Wg, Wo};
  float4 v = ((const float4*)srcs[g])[idx];
  half4 h = {(_Float16)v.x, (_Float16)v.y, (_Float16)v.z, (_Float16)v.w};
  _Float16* dst = (g < 4) ? (wcat + (size_t)g * 65536) : woh;
  *(half4*)(dst + (size_t)idx * 4) = h;
}

// ---------- K0: LayerNorm (no affine), one block per (b,s) row; fp16 out
__global__ __launch_bounds__(256) void k_ln(const float* __restrict__ x,
                                            _Float16* __restrict__ xnh){
  __shared__ float red[4];
  int row = blockIdx.x, t = threadIdx.x;
  float xv = x[(size_t)row * EE + t];
  float s  = blockSum(xv, red);
  float ss = blockSum(xv * xv, red);
  float mean = s * (1.0f / EE);
  float var  = ss * (1.0f / EE) - mean * mean;
  float rstd = rsqrtf(var + 1e-5f);
  xnh[(size_t)row * EE + t] = (_Float16)((xv - mean) * rstd);
}

// ---------- K1: q/k/v/gate projection as one 4096x1024x256 fp16 MFMA GEMM.
// Block = 64(M) x 64(N); wave w owns N-sub w*16. No LDS: A and B fragments
// are natural 16B/lane row-major global loads. N-major matrix id is
// block-uniform (64-col tile within a 256-col matrix).
__global__ __launch_bounds__(256) void k_proj(const _Float16* __restrict__ xnh,
    const _Float16* __restrict__ wcat, const float* __restrict__ bg,
    u16* __restrict__ qws, u16* __restrict__ kws,
    u16* __restrict__ vtws, float* __restrict__ gws){
  int t = threadIdx.x, wave = t >> 6, lane = t & 63;
  int q4 = lane >> 4, ln = lane & 15;
  int Mblk = blockIdx.x >> 4, Nblk = blockIdx.x & 15;
  int m0 = Mblk * 64, n0 = Nblk * 64 + wave * 16;
  int n = n0 + ln;
  const _Float16* brow = wcat + (size_t)n * EE;
  f32x4 acc[4];
  #pragma unroll
  for (int mb = 0; mb < 4; ++mb) acc[mb] = (f32x4){0.f,0.f,0.f,0.f};
  for (int k0 = 0; k0 < EE; k0 += 32){
    half8 bf = *(const half8*)(brow + k0 + q4 * 8);
    #pragma unroll
    for (int mb = 0; mb < 4; ++mb){
      half8 af = *(const half8*)(xnh + (size_t)(m0 + mb * 16 + ln) * EE + k0 + q4 * 8);
      acc[mb] = __builtin_amdgcn_mfma_f32_16x16x32_f16(af, bf, acc[mb], 0, 0, 0);
    }
  }
  int mat = n >> 8, c = n & 255;
  int h = c >> 5, d = c & 31;
  int b = m0 >> 11, s0 = (m0 & (SS - 1));
  size_t rowbase = ((size_t)b * HH + h) * SS;
  if (mat == 0){
    #pragma unroll
    for (int mb = 0; mb < 4; ++mb)
      #pragma unroll
      for (int r = 0; r < 4; ++r){
        int s = s0 + mb * 16 + q4 * 4 + r;
        qws[(rowbase + s) * DDh + d] = f2b(acc[mb][r] * 0.17677669529663687f);
      }
  } else if (mat == 1){
    #pragma unroll
    for (int mb = 0; mb < 4; ++mb)
      #pragma unroll
      for (int r = 0; r < 4; ++r){
        int s = s0 + mb * 16 + q4 * 4 + r;
        kws[(rowbase + s) * DDh + d] = f2b(acc[mb][r]);
      }
  } else if (mat == 2){
    // V^T: fixed (h,d) row, consecutive s -> one 8B store per m-block
    u16* vrow = vtws + (((size_t)b * HH + h) * DDh + d) * SS;
    #pragma unroll
    for (int mb = 0; mb < 4; ++mb){
      ushort4 pk;
      pk.x = f2b(acc[mb][0]); pk.y = f2b(acc[mb][1]);
      pk.z = f2b(acc[mb][2]); pk.w = f2b(acc[mb][3]);
      *(ushort4*)(vrow + s0 + mb * 16 + q4 * 4) = pk;
    }
  } else {
    float bgv = bg[c];
    #pragma unroll
    for (int mb = 0; mb < 4; ++mb)
      #pragma unroll
      for (int r = 0; r < 4; ++r){
        int s = s0 + mb * 16 + q4 * 4 + r;
        gws[(rowbase + s) * DDh + d] = 1.0f / (1.0f + __expf(-(acc[mb][r] + bgv)));
      }
  }
}

// ---------- K2: flash attention on MFMA. One wave = 16 query rows.
// S^T = K·Q^T so query index lives in lane&15 -> softmax reductions are
// 2 shfl_xor; P^T enters the PV MFMA (O^T = V^T·P^T) after a quad shuffle.
// Zero LDS, zero barriers. Epilogue writes fp16 gout for the MFMA k_out.
__global__ __launch_bounds__(256) void k_attn(const u16* __restrict__ qws,
    const u16* __restrict__ kws, const u16* __restrict__ vtws,
    const float* __restrict__ gws, const float* __restrict__ bias,
    const float* __restrict__ mask, _Float16* __restrict__ gouth){
  int t = threadIdx.x;
  int wave = t >> 6, lane = t & 63;
  int q4 = lane >> 4, ln = lane & 15;     // quad, lane-in-16
  int bh = blockIdx.x >> 5;               // 32 blocks per (b,h)
  int i0 = (blockIdx.x & 31) * 64 + wave * 16;
  int b = bh >> 3, h = bh & 7;

  // B-frag of Q^T: n=ln -> query i0+ln, k=q4*8+e -> d
  short8 qf = *(const short8*)(qws + (((size_t)bh * SS + i0 + ln) * DDh) + q4 * 8);

  const u16*  kb   = kws  + (size_t)bh * SS * DDh;
  const u16*  vt   = vtws + (size_t)bh * DDh * SS;
  const float* br  = bias + ((size_t)bh * SS + i0) * SS;
  const float* mrow= mask + (size_t)b * SS;

  f32x4 O0 = {0.f,0.f,0.f,0.f}, O1 = {0.f,0.f,0.f,0.f};
  float m_run = -INFINITY, l_run = 0.0f;
  const f32x4 zero = {0.f,0.f,0.f,0.f};

  for (int j0 = 0; j0 < SS; j0 += 32){
    short8 ka0 = *(const short8*)(kb + (size_t)(j0 + ln)      * DDh + q4 * 8);
    short8 ka1 = *(const short8*)(kb + (size_t)(j0 + 16 + ln) * DDh + q4 * 8);
    short8 va0 = *(const short8*)(vt + (size_t)ln        * SS + j0 + q4 * 8);
    short8 va1 = *(const short8*)(vt + (size_t)(16 + ln) * SS + j0 + q4 * 8);
    float4 bv0 = *(const float4*)(br + (size_t)ln * SS + j0 + q4 * 4);
    float4 bv1 = *(const float4*)(br + (size_t)ln * SS + j0 + 16 + q4 * 4);
    float4 mv0 = *(const float4*)(mrow + j0 + q4 * 4);
    float4 mv1 = *(const float4*)(mrow + j0 + 16 + q4 * 4);

    f32x4 s0 = __builtin_amdgcn_mfma_f32_16x16x32_bf16(ka0, qf, zero, 0, 0, 0);
    f32x4 s1 = __builtin_amdgcn_mfma_f32_16x16x32_bf16(ka1, qf, zero, 0, 0, 0);

    float lgv[8];
    lgv[0] = (mv0.x >= 0.5f) ? s0[0] + bv0.x : -32768.0f;
    lgv[1] = (mv0.y >= 0.5f) ? s0[1] + bv0.y : -32768.0f;
    lgv[2] = (mv0.z >= 0.5f) ? s0[2] + bv0.z : -32768.0f;
    lgv[3] = (mv0.w >= 0.5f) ? s0[3] + bv0.w : -32768.0f;
    lgv[4] = (mv1.x >= 0.5f) ? s1[0] + bv1.x : -32768.0f;
    lgv[5] = (mv1.y >= 0.5f) ? s1[1] + bv1.y : -32768.0f;
    lgv[6] = (mv1.z >= 0.5f) ? s1[2] + bv1.z : -32768.0f;
    lgv[7] = (mv1.w >= 0.5f) ? s1[3] + bv1.w : -32768.0f;

    float mt = lgv[0];
    #pragma unroll
    for (int r = 1; r < 8; ++r) mt = fmaxf(mt, lgv[r]);
    mt = fmaxf(mt, __shfl_xor(mt, 16, 64));
    mt = fmaxf(mt, __shfl_xor(mt, 32, 64));
    float m_new = fmaxf(m_run, mt);
    float alpha = __expf(m_run - m_new);
    float p[8], ts = 0.0f;
    #pragma unroll
    for (int r = 0; r < 8; ++r){ p[r] = __expf(lgv[r] - m_new); ts += p[r]; }
    ts += __shfl_xor(ts, 16, 64);
    ts += __shfl_xor(ts, 32, 64);
    l_run = l_run * alpha + ts;
    m_run = m_new;
    #pragma unroll
    for (int e = 0; e < 4; ++e){ O0[e] *= alpha; O1[e] *= alpha; }

    u32 P0 = pack2(p[0], p[1]), P1 = pack2(p[2], p[3]);
    u32 P2 = pack2(p[4], p[5]), P3 = pack2(p[6], p[7]);
    int sl  = (q4 & 1) * 32 + ln;
    int sl2 = sl + 16;
    u32 x0 = __shfl((int)P0, sl,  64), x1 = __shfl((int)P1, sl,  64);
    u32 x2 = __shfl((int)P2, sl,  64), x3 = __shfl((int)P3, sl,  64);
    u32 y0 = __shfl((int)P0, sl2, 64), y1 = __shfl((int)P1, sl2, 64);
    u32 y2 = __shfl((int)P2, sl2, 64), y3 = __shfl((int)P3, sl2, 64);
    bool lo = (q4 < 2);
    u32 bb[4];
    bb[0] = lo ? x0 : x2;  bb[1] = lo ? x1 : x3;
    bb[2] = lo ? y0 : y2;  bb[3] = lo ? y1 : y3;
    short8 pf = *(short8*)bb;

    O0 = __builtin_amdgcn_mfma_f32_16x16x32_bf16(va0, pf, O0, 0, 0, 0);
    O1 = __builtin_amdgcn_mfma_f32_16x16x32_bf16(va1, pf, O1, 0, 0, 0);
  }

  float inv = 1.0f / l_run;
  const float* gr = gws + ((size_t)bh * SS + i0 + ln) * DDh;
  float4 g0 = *(const float4*)(gr + q4 * 4);
  float4 g1 = *(const float4*)(gr + 16 + q4 * 4);
  _Float16* orow = gouth + ((size_t)b * SS + (i0 + ln)) * EE + h * DDh;
  half4 w0, w1;
  w0.x = (_Float16)(O0[0] * inv * g0.x);  w0.y = (_Float16)(O0[1] * inv * g0.y);
  w0.z = (_Float16)(O0[2] * inv * g0.z);  w0.w = (_Float16)(O0[3] * inv * g0.w);
  w1.x = (_Float16)(O1[0] * inv * g1.x);  w1.y = (_Float16)(O1[1] * inv * g1.y);
  w1.z = (_Float16)(O1[2] * inv * g1.z);  w1.w = (_Float16)(O1[3] * inv * g1.w);
  *(half4*)(orow + q4 * 4)      = w0;
  *(half4*)(orow + 16 + q4 * 4) = w1;
}

// ---------- K3: output projection as 4096x256x256 fp16 MFMA GEMM ----------
__global__ __launch_bounds__(256) void k_out(const _Float16* __restrict__ gouth,
    const _Float16* __restrict__ woh, const float* __restrict__ bo,
    float* __restrict__ out){
  int t = threadIdx.x, wave = t >> 6, lane = t & 63;
  int q4 = lane >> 4, ln = lane & 15;
  int Mblk = blockIdx.x >> 2, Nblk = blockIdx.x & 3;
  int m0 = Mblk * 64, n0 = Nblk * 64 + wave * 16;
  int n = n0 + ln;
  const _Float16* brow = woh + (size_t)n * EE;
  f32x4 acc[4];
  #pragma unroll
  for (int mb = 0; mb < 4; ++mb) acc[mb] = (f32x4){0.f,0.f,0.f,0.f};
  for (int k0 = 0; k0 < EE; k0 += 32){
    half8 bf = *(const half8*)(brow + k0 + q4 * 8);
    #pragma unroll
    for (int mb = 0; mb < 4; ++mb){
      half8 af = *(const half8*)(gouth + (size_t)(m0 + mb * 16 + ln) * EE + k0 + q4 * 8);
      acc[mb] = __builtin_amdgcn_mfma_f32_16x16x32_f16(af, bf, acc[mb], 0, 0, 0);
    }
  }
  float bov = bo[n];
  #pragma unroll
  for (int mb = 0; mb < 4; ++mb)
    #pragma unroll
    for (int r = 0; r < 4; ++r){
      int m = m0 + mb * 16 + q4 * 4 + r;
      out[(size_t)m * EE + n] = acc[mb][r] + bov;
    }
}

extern "C" void kernel_launch(void* const* d_in, const int* in_sizes, int n_in,
                              void* d_out, int out_size, void* d_ws, size_t ws_size,
                              hipStream_t stream){
  const float* x    = (const float*)d_in[0];
  const float* mask = (const float*)d_in[1];
  const float* bias = (const float*)d_in[2];
  const float* Wq   = (const float*)d_in[3];
  const float* Wk   = (const float*)d_in[4];
  const float* Wv   = (const float*)d_in[5];
  const float* Wg   = (const float*)d_in[6];
  const float* bg   = (const float*)d_in[7];
  const float* Wo   = (const float*)d_in[8];
  const float* bo   = (const float*)d_in[9];
  float* out = (float*)d_out;

  char* ws = (char*)d_ws;
  _Float16* xnh  = (_Float16*)ws;                // 2 MB  [4096][256] fp16 LN(x)
  u16*  qws  = (u16*) (ws + (2  << 20));         // 2 MB  [bh][S][32] bf16, pre-scaled
  u16*  kws  = (u16*) (ws + (4  << 20));         // 2 MB  [bh][S][32] bf16
  u16*  vtws = (u16*) (ws + (6  << 20));         // 2 MB  [bh][32][S] bf16 (transposed)
  float* gws = (float*)(ws + (8  << 20));        // 4 MB  [bh][S][32] f32 sigmoid gate
  _Float16* gouth = (_Float16*)(ws + (12 << 20));// 2 MB  [b][S][256] fp16 gated attn out
  _Float16* wcat  = (_Float16*)(ws + (14 << 20));// 512K  [1024][256] fp16 Wq|Wk|Wv|Wg
  _Float16* woh   = (_Float16*)(ws + (15 << 20));// 128K  [256][256] fp16 Wo

  hipLaunchKernelGGL(k_cvt,  dim3(320),                dim3(256), 0, stream,
                     Wq, Wk, Wv, Wg, Wo, wcat, woh);
  hipLaunchKernelGGL(k_ln,   dim3(BB * SS),            dim3(256), 0, stream, x, xnh);
  hipLaunchKernelGGL(k_proj, dim3(64 * 16),            dim3(256), 0, stream,
                     xnh, wcat, bg, qws, kws, vtws, gws);
  hipLaunchKernelGGL(k_attn, dim3(BB * HH * (SS / 64)), dim3(256), 0, stream,
                     qws, kws, vtws, gws, bias, mask, gouth);
  hipLaunchKernelGGL(k_out,  dim3(64 * 4),             dim3(256), 0, stream,
                     gouth, woh, bo, out);
}